// Round 8
// baseline (160.167 us; speedup 1.0000x reference)
//
#include <hip/hip_runtime.h>
#include <hip/hip_bf16.h>
#include <stdint.h>

// Problem constants
#define BB 4
#define NN 2048
#define DIMD 512
#define HH 8
#define DKK 64
#define MTOT (BB * NN)          // 8192
constexpr float SCALE = 0.125f;       // DK^-0.5
constexpr float L2E = 1.44269504089f; // log2(e)

typedef __attribute__((ext_vector_type(4))) float f32x4;
typedef __attribute__((ext_vector_type(2))) float f32x2;
typedef __attribute__((ext_vector_type(8))) short bf16x8;   // 8 bf16 (4 VGPRs)
typedef __attribute__((ext_vector_type(4))) _Float16 f16x4; // 4 f16 (2 VGPRs)
typedef __attribute__((ext_vector_type(8))) _Float16 f16x8; // 8 f16 (4 VGPRs)
typedef __attribute__((ext_vector_type(2))) __fp16 fp16v2;  // cvt_pkrtz result
typedef __attribute__((ext_vector_type(4))) __fp16 fp16v4;
typedef __attribute__((ext_vector_type(2))) unsigned int u32x2;

union pack8 { unsigned short s[8]; uint4 v; };
union fragu { u32x2 h[2]; bf16x8 v; };
union cat8u { f16x4 h[2]; f16x8 v; };

__device__ __forceinline__ unsigned short f2bf(float f) {
  union { float f; uint32_t u; } v; v.f = f;
  uint32_t u = v.u;
  return (unsigned short)((u + 0x7FFFu + ((u >> 16) & 1u)) >> 16); // RNE
}

__device__ __forceinline__ unsigned short f2h(float f) {
  union { _Float16 h; unsigned short u; } c; c.h = (_Float16)f;
  return c.u;
}

// LDS helpers for 8B-aligned rows: explicit b64 ops
__device__ __forceinline__ bf16x8 ld_frag(const unsigned short* p) {
  fragu f;
  f.h[0] = *(const u32x2*)p;
  f.h[1] = *(const u32x2*)(p + 4);
  return f.v;
}
__device__ __forceinline__ void st8(unsigned short* p, uint4 v) {
  *(u32x2*)p = (u32x2){v.x, v.y};
  *(u32x2*)(p + 4) = (u32x2){v.z, v.w};
}

__device__ __forceinline__ f16x8 cat8(f16x4 a, f16x4 b) {
  cat8u u; u.h[0] = a; u.h[1] = b; return u.v;
}

// K-row LDS permutation: bits (b4,b3,b2) -> (b2,b4,b3). After staging K row j
// at LDS row kperm(j), the QK mfma pair (u=2a,2a+1) leaves each lane holding
// P[j = a*32 + quad*8 + 0..7][i] — the NATIVE B-fragment of
// mfma_f32_16x16x32_f16 (no cross-lane shuffles). Verified R6 (passed).
__device__ __forceinline__ int kperm(int j) {
  return (j & 96) | ((j & 4) << 2) | ((j & 24) >> 1) | (j & 3);
}

// Input sv is PRE-SCALED by log2(e) (folded into qk_gemm epilogue), so
// e = 2^(-|sv|) = exp(-|x|) is one v_exp_f32 with -abs input modifiers.
// Returns sigmoid(x) - 0.5 packed to f16 (the +0.5 term = 0.5*rowsum(V),
// added from vsum_p in the attn epilogue).
__device__ __forceinline__ f16x4 sig_pack(f32x4 sv) {
  float e0 = __builtin_amdgcn_exp2f(-__builtin_fabsf(sv[0]));
  float e1 = __builtin_amdgcn_exp2f(-__builtin_fabsf(sv[1]));
  float e2 = __builtin_amdgcn_exp2f(-__builtin_fabsf(sv[2]));
  float e3 = __builtin_amdgcn_exp2f(-__builtin_fabsf(sv[3]));
  const f32x2 c3 = {-0.22184f, -0.22184f};
  const f32x2 c2 = {0.66550f, 0.66550f};
  const f32x2 c1 = {-0.94280f, -0.94280f};
  const f32x2 c0 = {0.49826f, 0.49826f};
  f32x2 eA = {e0, e1}, eB = {e2, e3};
  f32x2 pA = __builtin_elementwise_fma(
      __builtin_elementwise_fma(__builtin_elementwise_fma(c3, eA, c2), eA, c1),
      eA, c0);
  f32x2 pB = __builtin_elementwise_fma(
      __builtin_elementwise_fma(__builtin_elementwise_fma(c3, eB, c2), eB, c1),
      eB, c0);
  float r0 = __builtin_copysignf(pA.x, sv[0]);
  float r1 = __builtin_copysignf(pA.y, sv[1]);
  float r2 = __builtin_copysignf(pB.x, sv[2]);
  float r3 = __builtin_copysignf(pB.y, sv[3]);
  fp16v2 lo = __builtin_amdgcn_cvt_pkrtz(r0, r1);
  fp16v2 hi = __builtin_amdgcn_cvt_pkrtz(r2, r3);
  fp16v4 p;
  p.x = lo.x; p.y = lo.y; p.z = hi.x; p.w = hi.y;
  return __builtin_bit_cast(f16x4, p);
}

// ---------------------------------------------------------------------------
// prep_w: Wq/Wk -> Wt bf16 [N][K] via stride-68 LDS tile. 128 blocks.
//   (x-transpose moved into qk_gemm's grid — overlaps the GEMM.)
// ---------------------------------------------------------------------------
__global__ __launch_bounds__(256) void prep_w(const float* __restrict__ wq,
                                              const float* __restrict__ wk,
                                              unsigned short* __restrict__ wtq,
                                              unsigned short* __restrict__ wtk) {
  __shared__ __align__(16) unsigned short T[64][68];
  const int tid = threadIdx.x;
  int q = blockIdx.x;
  const float* w = (q >= 64) ? wk : wq;
  unsigned short* wt = (q >= 64) ? wtk : wtq;
  int r = q & 63;
  int kt = r >> 3, nt = r & 7;
  const int k0 = kt * 64, n0 = nt * 64;
#pragma unroll
  for (int rr = 0; rr < 16; rr++) {
    int idx = tid + rr * 256;
    int kl = idx >> 6, nl = idx & 63;
    T[nl][kl] = f2bf(w[(size_t)(k0 + kl) * DIMD + n0 + nl]);
  }
  __syncthreads();
#pragma unroll
  for (int rr = 0; rr < 2; rr++) {
    int idx = tid + rr * 256;
    int nl = idx >> 3, c = idx & 7;
    fragu f;
    f.h[0] = *(const u32x2*)&T[nl][c * 8];
    f.h[1] = *(const u32x2*)&T[nl][c * 8 + 4];
    uint4 v;
    v.x = f.h[0].x; v.y = f.h[0].y; v.z = f.h[1].x; v.w = f.h[1].y;
    *(uint4*)(wt + (size_t)(n0 + nl) * DIMD + k0 + c * 8) = v;
  }
}

// ---------------------------------------------------------------------------
// qk_gemm: grid (64, 10).
//   nb<8: 128x128 GEMM tile, 8 waves, register prefetch; A loaded from f32 x
//         with f2bf in the prefetch shadow; Q pre-scaled by log2(e).
//   nb>=8: x-transpose blocks (2 old 256-thr jobs per 512-thr block):
//         xtf f16 [B][DIM][N] + race-free vsum partials. Memory-bound work
//         overlaps the compute-bound GEMM blocks instead of serializing.
// ---------------------------------------------------------------------------
__global__ __launch_bounds__(512, 4) void qk_gemm(const float* __restrict__ x,
                                                  const unsigned short* __restrict__ wtq,
                                                  const unsigned short* __restrict__ wtk,
                                                  const float* __restrict__ bias,
                                                  unsigned short* __restrict__ qout,
                                                  unsigned short* __restrict__ kout,
                                                  unsigned short* __restrict__ xtf,
                                                  float* __restrict__ vsum_p) {
  const int mb = blockIdx.x, nb = blockIdx.y;
  const int tid = threadIdx.x;

  if (nb >= 8) {
    // ---- x-transpose + vsum partials (2 jobs of the old 256-thr version) ----
    __shared__ float Pred[2][4][64];
    const int g = tid >> 8, t = tid & 255;
    int q = (mb * 2 + (nb - 8)) * 2 + g; // 0..255
    int b = q >> 6, r = q & 63;
    int dt = r >> 3, nt = r & 7;
    int dl = t & 63, c = t >> 6;
    int d = dt * 64 + dl;
    int n0 = nt * 256 + c * 64;
    const float* xp = x + ((size_t)b * NN + n0) * DIMD + d;
    unsigned short* dp = xtf + ((size_t)b * DIMD + d) * NN + n0;
    float s = 0.f;
#pragma unroll
    for (int gg = 0; gg < 8; gg++) {
      pack8 pa;
#pragma unroll
      for (int k = 0; k < 8; k++) {
        float v = xp[(size_t)(gg * 8 + k) * DIMD];
        s += v;
        pa.s[k] = f2h(v);
      }
      *(uint4*)(dp + gg * 8) = pa.v;
    }
    Pred[g][c][dl] = s;
    __syncthreads();
    if (c == 0) {
      float tt = Pred[g][0][dl] + Pred[g][1][dl] + Pred[g][2][dl] + Pred[g][3][dl];
      vsum_p[((size_t)b * 8 + nt) * DIMD + d] = tt;
    }
    return;
  }

  __shared__ __align__(16) unsigned short Als[128][68];
  __shared__ __align__(16) unsigned short Bls[128][68];
  const bool isQ = (nb < 4);
  const unsigned short* wt = isQ ? wtq : wtk;
  unsigned short* outp = isQ ? qout : kout;
  const int n0 = (nb & 3) * 128, m0 = mb * 128;
  const int wave = tid >> 6, lane = tid & 63;
  const int quad = lane >> 4, l16 = lane & 15;
  const int wm = wave >> 2, wn = wave & 3;

  f32x4 acc[4][2];
#pragma unroll
  for (int a = 0; a < 4; a++)
#pragma unroll
    for (int c = 0; c < 2; c++) acc[a][c] = (f32x4){0.f, 0.f, 0.f, 0.f};

  const int srow[2] = {tid >> 3, (tid + 512) >> 3};
  const int scol = (tid & 7) * 8;
  uint4 pa[2], pb[2];

  auto loadA = [&](int r, int k0) -> uint4 {
    const float* ap = x + (size_t)(m0 + srow[r]) * DIMD + k0 + scol;
    float4 a = *(const float4*)ap;
    float4 b = *(const float4*)(ap + 4);
    pack8 p;
    p.s[0] = f2bf(a.x); p.s[1] = f2bf(a.y); p.s[2] = f2bf(a.z); p.s[3] = f2bf(a.w);
    p.s[4] = f2bf(b.x); p.s[5] = f2bf(b.y); p.s[6] = f2bf(b.z); p.s[7] = f2bf(b.w);
    return p.v;
  };

#pragma unroll
  for (int r = 0; r < 2; r++) {
    pa[r] = loadA(r, 0);
    pb[r] = *(const uint4*)(wt + (size_t)(n0 + srow[r]) * DIMD + scol);
  }

  for (int k0 = 0; k0 < DIMD; k0 += 64) {
    __syncthreads();
#pragma unroll
    for (int r = 0; r < 2; r++) {
      st8(&Als[srow[r]][scol], pa[r]);
      st8(&Bls[srow[r]][scol], pb[r]);
    }
    __syncthreads();
    if (k0 + 64 < DIMD) {
#pragma unroll
      for (int r = 0; r < 2; r++) {
        pa[r] = loadA(r, k0 + 64);
        pb[r] = *(const uint4*)(wt + (size_t)(n0 + srow[r]) * DIMD + k0 + 64 + scol);
      }
    }
#pragma unroll
    for (int ks = 0; ks < 2; ks++) {
      bf16x8 af[4], bfr[2];
#pragma unroll
      for (int t = 0; t < 4; t++)
        af[t] = ld_frag(&Als[wm * 64 + t * 16 + l16][quad * 8 + ks * 32]);
#pragma unroll
      for (int t = 0; t < 2; t++)
        bfr[t] = ld_frag(&Bls[wn * 32 + t * 16 + l16][quad * 8 + ks * 32]);
#pragma unroll
      for (int tm = 0; tm < 4; tm++)
#pragma unroll
        for (int tn = 0; tn < 2; tn++)
          acc[tm][tn] =
              __builtin_amdgcn_mfma_f32_16x16x32_bf16(af[tm], bfr[tn], acc[tm][tn], 0, 0, 0);
    }
  }
#pragma unroll
  for (int tm = 0; tm < 4; tm++) {
#pragma unroll
    for (int tn = 0; tn < 2; tn++) {
      int gcol = n0 + wn * 32 + tn * 16 + l16;
      float bl = isQ ? bias[gcol] * L2E : 0.f;
#pragma unroll
      for (int r = 0; r < 4; r++) {
        int row = m0 + wm * 64 + tm * 16 + quad * 4 + r;
        float v = acc[tm][tn][r];
        if (isQ) v = v * (SCALE * L2E) + bl;
        outp[(size_t)row * DIMD + gcol] = f2bf(v);
      }
    }
  }
}

// ---------------------------------------------------------------------------
// attn: O = (sigmoid(Q K^T)-0.5) V + 0.5*rowsum(V). R6 structure (kperm'd K,
//   PV on mfma_f32_16x16x32_f16, KVBLK=128) + R7: REGISTER DOUBLE-BUFFER of
//   K-fragments across a-iters (load kf[a+1] before computing a; static
//   2-slot arrays per rule #20) — hides the 8-b64 lgkm latency under the
//   previous a's MFMA+sigmoid chain. VGPR headroom: launch_bounds(512,4)
//   caps at 128; compiler sat at 64 without the dbuf.
// ---------------------------------------------------------------------------
__global__ __launch_bounds__(512, 4) void attn(const unsigned short* __restrict__ qb,
                                               const unsigned short* __restrict__ kb,
                                               const unsigned short* __restrict__ xtf,
                                               const float* __restrict__ vsum_p,
                                               float* __restrict__ out) {
  __shared__ __align__(16) char smem[68608];
  unsigned short* Kall = (unsigned short*)smem;        // [2 grp][128][68]
  unsigned short* Vall = Kall + 2 * 128 * 68;          // [2 grp][64][132]
  float* R0 = (float*)smem;                            // [128][66] combine

  const int bh = blockIdx.x, it = blockIdx.y;          // XCD swizzle: id%8==bh%8
  const int b = bh >> 3, h = bh & 7;
  const int i0 = it * 128;
  const int tid = threadIdx.x;
  const int lane = tid & 63;
  const int grp = tid >> 8;          // j-group 0/1
  const int wv = (tid >> 6) & 3;     // wave within group
  const int gtid = tid & 255;
  const int quad = lane >> 4, l16 = lane & 15;

  // Q B-fragments for 2 i-subtiles
  bf16x8 qf[2][2];
  int irow[2];
#pragma unroll
  for (int s_ = 0; s_ < 2; s_++) {
    irow[s_] = i0 + wv * 32 + s_ * 16 + l16;
    const unsigned short* qp = qb + ((size_t)b * NN + irow[s_]) * DIMD + h * DKK + quad * 8;
    qf[s_][0] = *(const bf16x8*)qp;
    qf[s_][1] = *(const bf16x8*)(qp + 32);
  }

  f32x4 o[2][4];
#pragma unroll
  for (int s_ = 0; s_ < 2; s_++)
#pragma unroll
    for (int td = 0; td < 4; td++) o[s_][td] = (f32x4){0.f, 0.f, 0.f, 0.f};

  const unsigned short* kbase = kb + (size_t)b * NN * DIMD + h * DKK;
  const unsigned short* vbase = xtf + ((size_t)b * DIMD + h * DKK) * NN;
  unsigned short* Kg = Kall + grp * (128 * 68);
  unsigned short* Vg = Vall + grp * (64 * 132);
  const int jbase = grp * 1024;

  const int krow = gtid >> 3, kcol = (gtid & 7) * 8;   // K: 32 rows/pass x 4
  const int vrow = gtid >> 4, vcol = (gtid & 15) * 8;  // V: 16 rows/pass x 4
  uint4 pk[4], pv[4];

  auto prefetch = [&](int t) {
    const int jb = jbase + t * 128;
#pragma unroll
    for (int r = 0; r < 4; r++) {
      pk[r] = *(const uint4*)(kbase + (size_t)(jb + krow + 32 * r) * DIMD + kcol);
      pv[r] = *(const uint4*)(vbase + (size_t)(vrow + 16 * r) * NN + jb + vcol);
    }
  };
  prefetch(0);

  auto loadK = [&](int a, bf16x8* kf) {
    kf[0] = ld_frag(&Kg[((2 * a) * 16 + l16) * 68 + quad * 8]);
    kf[1] = ld_frag(&Kg[((2 * a) * 16 + l16) * 68 + quad * 8 + 32]);
    kf[2] = ld_frag(&Kg[((2 * a + 1) * 16 + l16) * 68 + quad * 8]);
    kf[3] = ld_frag(&Kg[((2 * a + 1) * 16 + l16) * 68 + quad * 8 + 32]);
  };
  auto computeA = [&](int a, const bf16x8* kf) {
    f16x8 pf[2];
#pragma unroll
    for (int s_ = 0; s_ < 2; s_++) {
      f32x4 se = (f32x4){0.f, 0.f, 0.f, 0.f};
      f32x4 so = (f32x4){0.f, 0.f, 0.f, 0.f};
      se = __builtin_amdgcn_mfma_f32_16x16x32_bf16(kf[0], qf[s_][0], se, 0, 0, 0);
      se = __builtin_amdgcn_mfma_f32_16x16x32_bf16(kf[1], qf[s_][1], se, 0, 0, 0);
      so = __builtin_amdgcn_mfma_f32_16x16x32_bf16(kf[2], qf[s_][0], so, 0, 0, 0);
      so = __builtin_amdgcn_mfma_f32_16x16x32_bf16(kf[3], qf[s_][1], so, 0, 0, 0);
      pf[s_] = cat8(sig_pack(se), sig_pack(so));
    }
#pragma unroll
    for (int td = 0; td < 4; td++) {
      f16x8 vf = __builtin_bit_cast(
          f16x8, ld_frag(&Vg[(td * 16 + l16) * 132 + a * 32 + quad * 8]));
      o[0][td] = __builtin_amdgcn_mfma_f32_16x16x32_f16(vf, pf[0], o[0][td], 0, 0, 0);
      o[1][td] = __builtin_amdgcn_mfma_f32_16x16x32_f16(vf, pf[1], o[1][td], 0, 0, 0);
    }
  };

  for (int itr = 0; itr < 8; itr++) {
    __syncthreads();
#pragma unroll
    for (int r = 0; r < 4; r++) {
      st8(&Kg[kperm(krow + 32 * r) * 68 + kcol], pk[r]);
      st8(&Vg[(vrow + 16 * r) * 132 + vcol], pv[r]);
    }
    __syncthreads();
    if (itr < 7) prefetch(itr + 1);

    __builtin_amdgcn_s_setprio(1);
    // register double-buffer of K-fragments: kf[a+1] in flight during a
    bf16x8 kfA[4], kfB[4];
    loadK(0, kfA);
    loadK(1, kfB);
    computeA(0, kfA);
    loadK(2, kfA);
    computeA(1, kfB);
    loadK(3, kfB);
    computeA(2, kfA);
    computeA(3, kfB);
    __builtin_amdgcn_s_setprio(0);
  }

  // combine the two j-groups' partial O^T through LDS; group 0 adds the
  // 0.5*rowsum(V) fold (sum of 8 race-free prep partials) and stores.
  __syncthreads();
  if (grp == 1) {
#pragma unroll
    for (int s_ = 0; s_ < 2; s_++)
#pragma unroll
      for (int td = 0; td < 4; td++) {
        int base = (wv * 32 + s_ * 16 + l16) * 66 + td * 16 + quad * 4;
        *(f32x2*)&R0[base] = (f32x2){o[s_][td][0], o[s_][td][1]};
        *(f32x2*)&R0[base + 2] = (f32x2){o[s_][td][2], o[s_][td][3]};
      }
  }
  __syncthreads();
  if (grp == 0) {
    const float* vp = vsum_p + (size_t)b * 8 * DIMD + h * DKK;
    f32x4 vs[4];
#pragma unroll
    for (int td = 0; td < 4; td++) {
      f32x4 a = (f32x4){0.f, 0.f, 0.f, 0.f};
#pragma unroll
      for (int p = 0; p < 8; p++) {
        f32x4 t = *(const f32x4*)&vp[(size_t)p * DIMD + td * 16 + quad * 4];
        a[0] += t[0]; a[1] += t[1]; a[2] += t[2]; a[3] += t[3];
      }
      vs[td] = a;
    }
#pragma unroll
    for (int s_ = 0; s_ < 2; s_++) {
#pragma unroll
      for (int td = 0; td < 4; td++) {
        int base = (wv * 32 + s_ * 16 + l16) * 66 + td * 16 + quad * 4;
        f32x2 a = *(const f32x2*)&R0[base];
        f32x2 c = *(const f32x2*)&R0[base + 2];
        o[s_][td][0] += a.x + 0.5f * vs[td][0];
        o[s_][td][1] += a.y + 0.5f * vs[td][1];
        o[s_][td][2] += c.x + 0.5f * vs[td][2];
        o[s_][td][3] += c.y + 0.5f * vs[td][3];
        float* op = out + ((size_t)b * NN + irow[s_]) * DIMD + h * DKK + td * 16 + quad * 4;
        *(f32x4*)op = o[s_][td];
      }
    }
  }
}

// ---------------------------------------------------------------------------
extern "C" void kernel_launch(void* const* d_in, const int* in_sizes, int n_in,
                              void* d_out, int out_size, void* d_ws, size_t ws_size,
                              hipStream_t stream) {
  const float* x = (const float*)d_in[0];
  const float* Wq = (const float*)d_in[1];
  const float* Wk = (const float*)d_in[2];
  const float* bias = (const float*)d_in[3]; // [1,8,1,64] flat = 512
  float* out = (float*)d_out;

  unsigned short* ws = (unsigned short*)d_ws;
  unsigned short* xtf = ws;                        // 4,194,304 (f16 bits)
  unsigned short* wtq = xtf + (size_t)MTOT * DIMD; // 262,144
  unsigned short* wtk = wtq + (size_t)DIMD * DIMD; // 262,144
  unsigned short* qb = wtk + (size_t)DIMD * DIMD;  // 4,194,304
  unsigned short* kb = qb + (size_t)MTOT * DIMD;   // 4,194,304
  float* vsum_p = (float*)(kb + (size_t)MTOT * DIMD); // [4][8][512] f32 = 64 KB

  prep_w<<<dim3(128), 256, 0, stream>>>(Wq, Wk, wtq, wtk);
  qk_gemm<<<dim3(64, 10), 512, 0, stream>>>(x, wtq, wtk, bias, qb, kb, xtf, vsum_p);
  attn<<<dim3(32, 16), 512, 0, stream>>>(qb, kb, xtf, vsum_p, out);
}

// Round 9
// 146.487 us; speedup vs baseline: 1.0934x; 1.0934x over previous
//
#include <hip/hip_runtime.h>
#include <hip/hip_bf16.h>
#include <stdint.h>

// Problem constants
#define BB 4
#define NN 2048
#define DIMD 512
#define HH 8
#define DKK 64
#define MTOT (BB * NN)          // 8192
constexpr float SCALE = 0.125f;       // DK^-0.5
constexpr float L2E = 1.44269504089f; // log2(e)

typedef __attribute__((ext_vector_type(4))) float f32x4;
typedef __attribute__((ext_vector_type(2))) float f32x2;
typedef __attribute__((ext_vector_type(8))) short bf16x8;   // 8 bf16 (4 VGPRs)
typedef __attribute__((ext_vector_type(4))) _Float16 f16x4; // 4 f16 (2 VGPRs)
typedef __attribute__((ext_vector_type(8))) _Float16 f16x8; // 8 f16 (4 VGPRs)
typedef __attribute__((ext_vector_type(2))) __fp16 fp16v2;  // cvt_pkrtz result
typedef __attribute__((ext_vector_type(4))) __fp16 fp16v4;
typedef __attribute__((ext_vector_type(2))) unsigned int u32x2;

union pack8 { unsigned short s[8]; uint4 v; };
union fragu { u32x2 h[2]; bf16x8 v; };
union cat8u { f16x4 h[2]; f16x8 v; };

__device__ __forceinline__ unsigned short f2bf(float f) {
  union { float f; uint32_t u; } v; v.f = f;
  uint32_t u = v.u;
  return (unsigned short)((u + 0x7FFFu + ((u >> 16) & 1u)) >> 16); // RNE
}

__device__ __forceinline__ unsigned short f2h(float f) {
  union { _Float16 h; unsigned short u; } c; c.h = (_Float16)f;
  return c.u;
}

// LDS helpers for 8B-aligned rows: explicit b64 ops
__device__ __forceinline__ bf16x8 ld_frag(const unsigned short* p) {
  fragu f;
  f.h[0] = *(const u32x2*)p;
  f.h[1] = *(const u32x2*)(p + 4);
  return f.v;
}
__device__ __forceinline__ void st8(unsigned short* p, uint4 v) {
  *(u32x2*)p = (u32x2){v.x, v.y};
  *(u32x2*)(p + 4) = (u32x2){v.z, v.w};
}

__device__ __forceinline__ f16x8 cat8(f16x4 a, f16x4 b) {
  cat8u u; u.h[0] = a; u.h[1] = b; return u.v;
}

// K-row LDS permutation: bits (b4,b3,b2) -> (b2,b4,b3). After staging K row j
// at LDS row kperm(j), the QK mfma pair (u=2a,2a+1) leaves each lane holding
// P[j = a*32 + quad*8 + 0..7][i] — the NATIVE B-fragment of
// mfma_f32_16x16x32_f16 (no cross-lane shuffles). Verified R6 (passed).
__device__ __forceinline__ int kperm(int j) {
  return (j & 96) | ((j & 4) << 2) | ((j & 24) >> 1) | (j & 3);
}

// Input sv is PRE-SCALED by log2(e) (folded into qk_gemm epilogue), so
// e = 2^(-|sv|) = exp(-|x|) is one v_exp_f32 with -abs input modifiers.
// Returns sigmoid(x) - 0.5 packed to f16 (the +0.5 term = 0.5*rowsum(V),
// added from vsum_p in the attn epilogue).
__device__ __forceinline__ f16x4 sig_pack(f32x4 sv) {
  float e0 = __builtin_amdgcn_exp2f(-__builtin_fabsf(sv[0]));
  float e1 = __builtin_amdgcn_exp2f(-__builtin_fabsf(sv[1]));
  float e2 = __builtin_amdgcn_exp2f(-__builtin_fabsf(sv[2]));
  float e3 = __builtin_amdgcn_exp2f(-__builtin_fabsf(sv[3]));
  const f32x2 c3 = {-0.22184f, -0.22184f};
  const f32x2 c2 = {0.66550f, 0.66550f};
  const f32x2 c1 = {-0.94280f, -0.94280f};
  const f32x2 c0 = {0.49826f, 0.49826f};
  f32x2 eA = {e0, e1}, eB = {e2, e3};
  f32x2 pA = __builtin_elementwise_fma(
      __builtin_elementwise_fma(__builtin_elementwise_fma(c3, eA, c2), eA, c1),
      eA, c0);
  f32x2 pB = __builtin_elementwise_fma(
      __builtin_elementwise_fma(__builtin_elementwise_fma(c3, eB, c2), eB, c1),
      eB, c0);
  float r0 = __builtin_copysignf(pA.x, sv[0]);
  float r1 = __builtin_copysignf(pA.y, sv[1]);
  float r2 = __builtin_copysignf(pB.x, sv[2]);
  float r3 = __builtin_copysignf(pB.y, sv[3]);
  fp16v2 lo = __builtin_amdgcn_cvt_pkrtz(r0, r1);
  fp16v2 hi = __builtin_amdgcn_cvt_pkrtz(r2, r3);
  fp16v4 p;
  p.x = lo.x; p.y = lo.y; p.z = hi.x; p.w = hi.y;
  return __builtin_bit_cast(f16x4, p);
}

// ---------------------------------------------------------------------------
// prep (single launch — fusion into qk_gemm measured HARMFUL in R8: delaying
// xtf writes leaves dirty L2 lines that evict attn's K/V working set):
//   blocks [0,256):   xtf f16 [B][DIM][N] — transpose; reduces per-block
//                     V-partials into vsum_p[b][nt][d] (race-free).
//   blocks [256,384): Wq/Wk -> Wt bf16 [N][K] via stride-68 LDS tile
// ---------------------------------------------------------------------------
__global__ __launch_bounds__(256) void prep(const float* __restrict__ x,
                                            const float* __restrict__ wq,
                                            const float* __restrict__ wk,
                                            unsigned short* __restrict__ xtf,
                                            unsigned short* __restrict__ wtq,
                                            unsigned short* __restrict__ wtk,
                                            float* __restrict__ vsum_p) {
  const int bx = blockIdx.x, tid = threadIdx.x;
  if (bx < 256) {
    __shared__ float Pred[4][64];
    int q = bx;
    int b = q >> 6, r = q & 63;
    int dt = r >> 3, nt = r & 7;
    int dl = tid & 63, c = tid >> 6;
    int d = dt * 64 + dl;
    int n0 = nt * 256 + c * 64;
    const float* xp = x + ((size_t)b * NN + n0) * DIMD + d;
    unsigned short* dp = xtf + ((size_t)b * DIMD + d) * NN + n0;
    float s = 0.f;
#pragma unroll
    for (int g = 0; g < 8; g++) {
      pack8 pa;
#pragma unroll
      for (int k = 0; k < 8; k++) {
        float v = xp[(size_t)(g * 8 + k) * DIMD];
        s += v;
        pa.s[k] = f2h(v);
      }
      *(uint4*)(dp + g * 8) = pa.v;
    }
    Pred[c][dl] = s;
    __syncthreads();
    if (c == 0) {
      float t = Pred[0][dl] + Pred[1][dl] + Pred[2][dl] + Pred[3][dl];
      vsum_p[((size_t)b * 8 + nt) * DIMD + d] = t;
    }
  } else {
    __shared__ __align__(16) unsigned short T[64][68];
    int q = bx - 256;
    const float* w = (q >= 64) ? wk : wq;
    unsigned short* wt = (q >= 64) ? wtk : wtq;
    int r = q & 63;
    int kt = r >> 3, nt = r & 7;
    const int k0 = kt * 64, n0 = nt * 64;
#pragma unroll
    for (int rr = 0; rr < 16; rr++) {
      int idx = tid + rr * 256;
      int kl = idx >> 6, nl = idx & 63;
      T[nl][kl] = f2bf(w[(size_t)(k0 + kl) * DIMD + n0 + nl]);
    }
    __syncthreads();
#pragma unroll
    for (int rr = 0; rr < 2; rr++) {
      int idx = tid + rr * 256;
      int nl = idx >> 3, c = idx & 7;
      fragu f;
      f.h[0] = *(const u32x2*)&T[nl][c * 8];
      f.h[1] = *(const u32x2*)&T[nl][c * 8 + 4];
      uint4 v;
      v.x = f.h[0].x; v.y = f.h[0].y; v.z = f.h[1].x; v.w = f.h[1].y;
      *(uint4*)(wt + (size_t)(n0 + nl) * DIMD + k0 + c * 8) = v;
    }
  }
}

// ---------------------------------------------------------------------------
// qk_gemm: 128x128 tile, 512 threads = 8 waves (2wm x 4wn), register
//   prefetch; A loaded from f32 x with f2bf in the prefetch shadow.
//   Q output pre-scaled by log2(e) for the exp2 sigmoid. (R5/R6 version.)
// ---------------------------------------------------------------------------
__global__ __launch_bounds__(512, 4) void qk_gemm(const float* __restrict__ x,
                                                  const unsigned short* __restrict__ wtq,
                                                  const unsigned short* __restrict__ wtk,
                                                  const float* __restrict__ bias,
                                                  unsigned short* __restrict__ qout,
                                                  unsigned short* __restrict__ kout) {
  __shared__ __align__(16) unsigned short Als[128][68];
  __shared__ __align__(16) unsigned short Bls[128][68];
  const int mb = blockIdx.x, nb = blockIdx.y;
  const bool isQ = (nb < 4);
  const unsigned short* wt = isQ ? wtq : wtk;
  unsigned short* outp = isQ ? qout : kout;
  const int n0 = (nb & 3) * 128, m0 = mb * 128;
  const int tid = threadIdx.x;
  const int wave = tid >> 6, lane = tid & 63;
  const int quad = lane >> 4, l16 = lane & 15;
  const int wm = wave >> 2, wn = wave & 3;

  f32x4 acc[4][2];
#pragma unroll
  for (int a = 0; a < 4; a++)
#pragma unroll
    for (int c = 0; c < 2; c++) acc[a][c] = (f32x4){0.f, 0.f, 0.f, 0.f};

  const int srow[2] = {tid >> 3, (tid + 512) >> 3};
  const int scol = (tid & 7) * 8;
  uint4 pa[2], pb[2];

  auto loadA = [&](int r, int k0) -> uint4 {
    const float* ap = x + (size_t)(m0 + srow[r]) * DIMD + k0 + scol;
    float4 a = *(const float4*)ap;
    float4 b = *(const float4*)(ap + 4);
    pack8 p;
    p.s[0] = f2bf(a.x); p.s[1] = f2bf(a.y); p.s[2] = f2bf(a.z); p.s[3] = f2bf(a.w);
    p.s[4] = f2bf(b.x); p.s[5] = f2bf(b.y); p.s[6] = f2bf(b.z); p.s[7] = f2bf(b.w);
    return p.v;
  };

#pragma unroll
  for (int r = 0; r < 2; r++) {
    pa[r] = loadA(r, 0);
    pb[r] = *(const uint4*)(wt + (size_t)(n0 + srow[r]) * DIMD + scol);
  }

  for (int k0 = 0; k0 < DIMD; k0 += 64) {
    __syncthreads();
#pragma unroll
    for (int r = 0; r < 2; r++) {
      st8(&Als[srow[r]][scol], pa[r]);
      st8(&Bls[srow[r]][scol], pb[r]);
    }
    __syncthreads();
    if (k0 + 64 < DIMD) {
#pragma unroll
      for (int r = 0; r < 2; r++) {
        pa[r] = loadA(r, k0 + 64);
        pb[r] = *(const uint4*)(wt + (size_t)(n0 + srow[r]) * DIMD + k0 + 64 + scol);
      }
    }
#pragma unroll
    for (int ks = 0; ks < 2; ks++) {
      bf16x8 af[4], bfr[2];
#pragma unroll
      for (int t = 0; t < 4; t++)
        af[t] = ld_frag(&Als[wm * 64 + t * 16 + l16][quad * 8 + ks * 32]);
#pragma unroll
      for (int t = 0; t < 2; t++)
        bfr[t] = ld_frag(&Bls[wn * 32 + t * 16 + l16][quad * 8 + ks * 32]);
#pragma unroll
      for (int tm = 0; tm < 4; tm++)
#pragma unroll
        for (int tn = 0; tn < 2; tn++)
          acc[tm][tn] =
              __builtin_amdgcn_mfma_f32_16x16x32_bf16(af[tm], bfr[tn], acc[tm][tn], 0, 0, 0);
    }
  }
#pragma unroll
  for (int tm = 0; tm < 4; tm++) {
#pragma unroll
    for (int tn = 0; tn < 2; tn++) {
      int gcol = n0 + wn * 32 + tn * 16 + l16;
      float bl = isQ ? bias[gcol] * L2E : 0.f;
#pragma unroll
      for (int r = 0; r < 4; r++) {
        int row = m0 + wm * 64 + tm * 16 + quad * 4 + r;
        float v = acc[tm][tn][r];
        if (isQ) v = v * (SCALE * L2E) + bl;
        outp[(size_t)row * DIMD + gcol] = f2bf(v);
      }
    }
  }
}

// ---------------------------------------------------------------------------
// attn: O = (sigmoid(Q K^T)-0.5) V + 0.5*rowsum(V). EXACT R6 structure
//   (best measured: 63.6 us steady): kperm'd K, PV on mfma_f32_16x16x32_f16,
//   KVBLK=128, BM=128, 512 thr = 2 j-groups x 4 waves, wave = 2 i-subtiles,
//   grid (bh,it) XCD swizzle. R9 tweak: next-tile global loads issued
//   BEFORE the post-staging barrier (issue-early, T14). R7's reg-dbuf and
//   transpose-fusion both REVERTED (measured regressions, R8).
// ---------------------------------------------------------------------------
__global__ __launch_bounds__(512, 4) void attn(const unsigned short* __restrict__ qb,
                                               const unsigned short* __restrict__ kb,
                                               const unsigned short* __restrict__ xtf,
                                               const float* __restrict__ vsum_p,
                                               float* __restrict__ out) {
  __shared__ __align__(16) char smem[68608];
  unsigned short* Kall = (unsigned short*)smem;        // [2 grp][128][68]
  unsigned short* Vall = Kall + 2 * 128 * 68;          // [2 grp][64][132]
  float* R0 = (float*)smem;                            // [128][66] combine

  const int bh = blockIdx.x, it = blockIdx.y;          // XCD swizzle: id%8==bh%8
  const int b = bh >> 3, h = bh & 7;
  const int i0 = it * 128;
  const int tid = threadIdx.x;
  const int lane = tid & 63;
  const int grp = tid >> 8;          // j-group 0/1
  const int wv = (tid >> 6) & 3;     // wave within group
  const int gtid = tid & 255;
  const int quad = lane >> 4, l16 = lane & 15;

  // Q B-fragments for 2 i-subtiles
  bf16x8 qf[2][2];
  int irow[2];
#pragma unroll
  for (int s_ = 0; s_ < 2; s_++) {
    irow[s_] = i0 + wv * 32 + s_ * 16 + l16;
    const unsigned short* qp = qb + ((size_t)b * NN + irow[s_]) * DIMD + h * DKK + quad * 8;
    qf[s_][0] = *(const bf16x8*)qp;
    qf[s_][1] = *(const bf16x8*)(qp + 32);
  }

  f32x4 o[2][4];
#pragma unroll
  for (int s_ = 0; s_ < 2; s_++)
#pragma unroll
    for (int td = 0; td < 4; td++) o[s_][td] = (f32x4){0.f, 0.f, 0.f, 0.f};

  const unsigned short* kbase = kb + (size_t)b * NN * DIMD + h * DKK;
  const unsigned short* vbase = xtf + ((size_t)b * DIMD + h * DKK) * NN;
  unsigned short* Kg = Kall + grp * (128 * 68);
  unsigned short* Vg = Vall + grp * (64 * 132);
  const int jbase = grp * 1024;

  const int krow = gtid >> 3, kcol = (gtid & 7) * 8;   // K: 32 rows/pass x 4
  const int vrow = gtid >> 4, vcol = (gtid & 15) * 8;  // V: 16 rows/pass x 4
  uint4 pk[4], pv[4];

  auto prefetch = [&](int t) {
    const int jb = jbase + t * 128;
#pragma unroll
    for (int r = 0; r < 4; r++) {
      pk[r] = *(const uint4*)(kbase + (size_t)(jb + krow + 32 * r) * DIMD + kcol);
      pv[r] = *(const uint4*)(vbase + (size_t)(vrow + 16 * r) * NN + jb + vcol);
    }
  };
  prefetch(0);

  for (int itr = 0; itr < 8; itr++) {
    __syncthreads();
#pragma unroll
    for (int r = 0; r < 4; r++) {
      st8(&Kg[kperm(krow + 32 * r) * 68 + kcol], pk[r]);
      st8(&Vg[(vrow + 16 * r) * 132 + vcol], pv[r]);
    }
    if (itr < 7) prefetch(itr + 1);  // issue-early: before the barrier
    __syncthreads();

    __builtin_amdgcn_s_setprio(1);
#pragma unroll
    for (int a = 0; a < 4; a++) {
      bf16x8 ke0 = ld_frag(&Kg[((2 * a) * 16 + l16) * 68 + quad * 8]);
      bf16x8 ke1 = ld_frag(&Kg[((2 * a) * 16 + l16) * 68 + quad * 8 + 32]);
      bf16x8 ko0 = ld_frag(&Kg[((2 * a + 1) * 16 + l16) * 68 + quad * 8]);
      bf16x8 ko1 = ld_frag(&Kg[((2 * a + 1) * 16 + l16) * 68 + quad * 8 + 32]);
      f16x8 pf[2];
#pragma unroll
      for (int s_ = 0; s_ < 2; s_++) {
        f32x4 se = (f32x4){0.f, 0.f, 0.f, 0.f};
        f32x4 so = (f32x4){0.f, 0.f, 0.f, 0.f};
        se = __builtin_amdgcn_mfma_f32_16x16x32_bf16(ke0, qf[s_][0], se, 0, 0, 0);
        se = __builtin_amdgcn_mfma_f32_16x16x32_bf16(ke1, qf[s_][1], se, 0, 0, 0);
        so = __builtin_amdgcn_mfma_f32_16x16x32_bf16(ko0, qf[s_][0], so, 0, 0, 0);
        so = __builtin_amdgcn_mfma_f32_16x16x32_bf16(ko1, qf[s_][1], so, 0, 0, 0);
        pf[s_] = cat8(sig_pack(se), sig_pack(so));
      }
#pragma unroll
      for (int td = 0; td < 4; td++) {
        f16x8 vf = __builtin_bit_cast(
            f16x8, ld_frag(&Vg[(td * 16 + l16) * 132 + a * 32 + quad * 8]));
        o[0][td] = __builtin_amdgcn_mfma_f32_16x16x32_f16(vf, pf[0], o[0][td], 0, 0, 0);
        o[1][td] = __builtin_amdgcn_mfma_f32_16x16x32_f16(vf, pf[1], o[1][td], 0, 0, 0);
      }
    }
    __builtin_amdgcn_s_setprio(0);
  }

  // combine the two j-groups' partial O^T through LDS; group 0 adds the
  // 0.5*rowsum(V) fold (sum of 8 race-free prep partials) and stores.
  __syncthreads();
  if (grp == 1) {
#pragma unroll
    for (int s_ = 0; s_ < 2; s_++)
#pragma unroll
      for (int td = 0; td < 4; td++) {
        int base = (wv * 32 + s_ * 16 + l16) * 66 + td * 16 + quad * 4;
        *(f32x2*)&R0[base] = (f32x2){o[s_][td][0], o[s_][td][1]};
        *(f32x2*)&R0[base + 2] = (f32x2){o[s_][td][2], o[s_][td][3]};
      }
  }
  __syncthreads();
  if (grp == 0) {
    const float* vp = vsum_p + (size_t)b * 8 * DIMD + h * DKK;
    f32x4 vs[4];
#pragma unroll
    for (int td = 0; td < 4; td++) {
      f32x4 a = (f32x4){0.f, 0.f, 0.f, 0.f};
#pragma unroll
      for (int p = 0; p < 8; p++) {
        f32x4 t = *(const f32x4*)&vp[(size_t)p * DIMD + td * 16 + quad * 4];
        a[0] += t[0]; a[1] += t[1]; a[2] += t[2]; a[3] += t[3];
      }
      vs[td] = a;
    }
#pragma unroll
    for (int s_ = 0; s_ < 2; s_++) {
#pragma unroll
      for (int td = 0; td < 4; td++) {
        int base = (wv * 32 + s_ * 16 + l16) * 66 + td * 16 + quad * 4;
        f32x2 a = *(const f32x2*)&R0[base];
        f32x2 c = *(const f32x2*)&R0[base + 2];
        o[s_][td][0] += a.x + 0.5f * vs[td][0];
        o[s_][td][1] += a.y + 0.5f * vs[td][1];
        o[s_][td][2] += c.x + 0.5f * vs[td][2];
        o[s_][td][3] += c.y + 0.5f * vs[td][3];
        float* op = out + ((size_t)b * NN + irow[s_]) * DIMD + h * DKK + td * 16 + quad * 4;
        *(f32x4*)op = o[s_][td];
      }
    }
  }
}

// ---------------------------------------------------------------------------
extern "C" void kernel_launch(void* const* d_in, const int* in_sizes, int n_in,
                              void* d_out, int out_size, void* d_ws, size_t ws_size,
                              hipStream_t stream) {
  const float* x = (const float*)d_in[0];
  const float* Wq = (const float*)d_in[1];
  const float* Wk = (const float*)d_in[2];
  const float* bias = (const float*)d_in[3]; // [1,8,1,64] flat = 512
  float* out = (float*)d_out;

  unsigned short* ws = (unsigned short*)d_ws;
  unsigned short* xtf = ws;                        // 4,194,304 (f16 bits)
  unsigned short* wtq = xtf + (size_t)MTOT * DIMD; // 262,144
  unsigned short* wtk = wtq + (size_t)DIMD * DIMD; // 262,144
  unsigned short* qb = wtk + (size_t)DIMD * DIMD;  // 4,194,304
  unsigned short* kb = qb + (size_t)MTOT * DIMD;   // 4,194,304
  float* vsum_p = (float*)(kb + (size_t)MTOT * DIMD); // [4][8][512] f32 = 64 KB

  prep<<<dim3(384), 256, 0, stream>>>(x, Wq, Wk, xtf, wtq, wtk, vsum_p);
  qk_gemm<<<dim3(64, 8), 512, 0, stream>>>(x, wtq, wtk, bias, qb, kb);
  attn<<<dim3(32, 16), 512, 0, stream>>>(qb, kb, xtf, vsum_p, out);
}